// Round 4
// baseline (522.415 us; speedup 1.0000x reference)
//
#include <hip/hip_runtime.h>
#include <cstdint>

#define T_TOKENS 4096
#define HDIM 2048
#define IDIM 1024
#define NEXP 8
#define NTOT 12
#define MAX_SLOTS 8320   // 8192 + 128 pad for tile overshoot reads

typedef __bf16 bf16x8_t __attribute__((ext_vector_type(8)));
typedef float f32x4_t __attribute__((ext_vector_type(4)));
typedef unsigned short u16x8_t __attribute__((ext_vector_type(8)));
typedef unsigned short u16x4_t __attribute__((ext_vector_type(4)));

#define WAITV(N) asm volatile("s_waitcnt vmcnt(" #N ")" ::: "memory")
#define CFENCE asm volatile("" ::: "memory")

__device__ __forceinline__ unsigned short f2bf(float f) {
    unsigned int u = __builtin_bit_cast(unsigned int, f);
    u += 0x7fffu + ((u >> 16) & 1u);
    return (unsigned short)(u >> 16);
}
__device__ __forceinline__ float bfu2f(unsigned short u) {
    unsigned int v = ((unsigned int)u) << 16;
    return __builtin_bit_cast(float, v);
}
// async global->LDS, 16B per lane; LDS dest = wave-uniform base + lane*16
__device__ __forceinline__ void async16(const unsigned short* g, unsigned short* l) {
    __builtin_amdgcn_global_load_lds(
        (const unsigned int __attribute__((address_space(1)))*)g,
        (unsigned int __attribute__((address_space(3)))*)l,
        16, 0, 0);
}
// read 16 fp32, convert RNE to bf16, write 32B to LDS (fallback path only)
__device__ __forceinline__ void cvt16(const float* src, unsigned short* dst) {
    f32x4_t f0 = ((const f32x4_t*)src)[0];
    f32x4_t f1 = ((const f32x4_t*)src)[1];
    f32x4_t f2 = ((const f32x4_t*)src)[2];
    f32x4_t f3 = ((const f32x4_t*)src)[3];
    u16x8_t a, b;
#pragma unroll
    for (int j = 0; j < 4; ++j) { a[j] = f2bf(f0[j]); a[4 + j] = f2bf(f1[j]); }
#pragma unroll
    for (int j = 0; j < 4; ++j) { b[j] = f2bf(f2[j]); b[4 + j] = f2bf(f3[j]); }
    ((u16x8_t*)dst)[0] = a;
    ((u16x8_t*)dst)[1] = b;
}

// ---------------- zero-init metadata ----------------
__global__ void init_kernel(int* __restrict__ meta) {
    int i = threadIdx.x;
    if (i < 32) meta[i] = 0;
}

__global__ void noop_kernel() {}

// ---------------- one-shot weight convert:
//   guwb[e][p][h]: p in [0,2048); j=p>>5, r=p&31; r<16 -> gate[e][16j+r][h], else up[e][16j+r-16][h]
//   dwb: straight fp32->bf16 of down_w
__global__ void pack_w_kernel(const float* __restrict__ gw, const float* __restrict__ uw,
                              const float* __restrict__ dw,
                              unsigned short* __restrict__ guwb,
                              unsigned short* __restrict__ dwb) {
    const int n8_gu = NEXP * 2 * IDIM * HDIM / 8;  // 4194304
    const int n8_d = NEXP * HDIM * IDIM / 8;       // 2097152
    int stride = gridDim.x * blockDim.x;
    for (int i = blockIdx.x * blockDim.x + threadIdx.x; i < n8_gu + n8_d; i += stride) {
        if (i < n8_gu) {
            size_t f = (size_t)i * 8;
            int h = (int)(f & (HDIM - 1));
            int p = (int)((f >> 11) & 2047);
            int e = (int)(f >> 22);
            int j = p >> 5, r = p & 31;
            const float* base = (r < 16) ? gw : uw;
            const float* src = base + ((size_t)e * IDIM + 16 * j + (r & 15)) * HDIM + h;
            f32x4_t a = ((const f32x4_t*)src)[0];
            f32x4_t b = ((const f32x4_t*)src)[1];
            u16x8_t o;
#pragma unroll
            for (int q = 0; q < 4; ++q) { o[q] = f2bf(a[q]); o[4 + q] = f2bf(b[q]); }
            ((u16x8_t*)guwb)[i] = o;
        } else {
            int k = i - n8_gu;
            const f32x4_t* p4 = (const f32x4_t*)(dw + (size_t)k * 8);
            f32x4_t a = p4[0], b = p4[1];
            u16x8_t o;
#pragma unroll
            for (int q = 0; q < 4; ++q) { o[q] = f2bf(a[q]); o[4 + q] = f2bf(b[q]); }
            ((u16x8_t*)dwb)[k] = o;
        }
    }
}

// ---------------- Router (fp32): logits->softmax->top2; also emits bf16 x ----------------
__global__ void router_kernel(const float* __restrict__ x,
                              const float* __restrict__ cw,
                              const float* __restrict__ bias,
                              int* __restrict__ counts,
                              int* __restrict__ tok_e,
                              float* __restrict__ tok_w,
                              float* __restrict__ zero_w,
                              unsigned short* __restrict__ xb) {
    const int token = blockIdx.x;
    const int ln = threadIdx.x;  // 0..63
    const float* xr = x + (size_t)token * HDIM;
    float acc[NTOT];
#pragma unroll
    for (int e = 0; e < NTOT; ++e) acc[e] = 0.f;
    for (int h0 = ln * 4; h0 < HDIM; h0 += 256) {
        f32x4_t xv = *(const f32x4_t*)(xr + h0);
        if (xb) {
            u16x4_t o;
#pragma unroll
            for (int j = 0; j < 4; ++j) o[j] = f2bf(xv[j]);
            *(u16x4_t*)(xb + (size_t)token * HDIM + h0) = o;
        }
#pragma unroll
        for (int e = 0; e < NTOT; ++e) {
            f32x4_t wv = *(const f32x4_t*)(cw + e * HDIM + h0);
            acc[e] += xv[0] * wv[0] + xv[1] * wv[1] + xv[2] * wv[2] + xv[3] * wv[3];
        }
    }
#pragma unroll
    for (int e = 0; e < NTOT; ++e) {
        float v = acc[e];
#pragma unroll
        for (int s = 32; s > 0; s >>= 1) v += __shfl_xor(v, s, 64);
        acc[e] = v;
    }
    if (ln == 0) {
        float mx = acc[0];
#pragma unroll
        for (int e = 1; e < NTOT; ++e) mx = fmaxf(mx, acc[e]);
        float p[NTOT];
        float sum = 0.f;
#pragma unroll
        for (int e = 0; e < NTOT; ++e) { p[e] = __expf(acc[e] - mx); sum += p[e]; }
        float inv = 1.f / sum;
#pragma unroll
        for (int e = 0; e < NTOT; ++e) p[e] *= inv;
        float b[NTOT];
#pragma unroll
        for (int e = 0; e < NTOT; ++e) b[e] = p[e] + bias[e];
        int i0 = 0; float v0 = b[0];
#pragma unroll
        for (int e = 1; e < NTOT; ++e) if (b[e] > v0) { v0 = b[e]; i0 = e; }
        int i1 = -1; float v1 = -3.0e38f;
#pragma unroll
        for (int e = 0; e < NTOT; ++e) if (e != i0 && b[e] > v1) { v1 = b[e]; i1 = e; }
        if (i1 < 0) i1 = (i0 == 0) ? 1 : 0;  // defensive
        float w0 = p[i0] * 1.5f, w1 = p[i1] * 1.5f;
        tok_e[2 * token] = i0; tok_e[2 * token + 1] = i1;
        tok_w[2 * token] = w0; tok_w[2 * token + 1] = w1;
        float zw = 0.f;
        if (i0 >= NEXP) zw += w0; else atomicAdd(&counts[i0], 1);
        if (i1 >= NEXP) zw += w1; else atomicAdd(&counts[i1], 1);
        zero_w[token] = zw;
    }
}

// ---------------- prefix scan over 8 experts ----------------
__global__ void scan_kernel(const int* __restrict__ counts, int* __restrict__ offs) {
    if (threadIdx.x == 0 && blockIdx.x == 0) {
        int a = 0;
        for (int e = 0; e < NEXP; ++e) {
            offs[e] = a;
            int c = counts[e];
            if (c < 0) c = 0;
            if (c > T_TOKENS) c = T_TOKENS;
            a += c;
        }
        if (a > 2 * T_TOKENS) a = 2 * T_TOKENS;
        offs[NEXP] = a;
    }
}

// ---------------- place tokens into per-expert contiguous lists ----------------
__global__ void place_kernel(const int* __restrict__ tok_e, const float* __restrict__ tok_w,
                             const int* __restrict__ offs, int* __restrict__ fill,
                             int* __restrict__ token_list, float* __restrict__ slot_w,
                             int* __restrict__ map) {
    int token = blockIdx.x * blockDim.x + threadIdx.x;
    if (token >= T_TOKENS) return;
#pragma unroll
    for (int j = 0; j < 2; ++j) {
        int e = tok_e[2 * token + j];
        int m = -1;
        if (e >= 0 && e < NEXP) {
            int pos = atomicAdd(&fill[e], 1);
            int slot = offs[e] + pos;
            if (slot >= 0 && slot < 2 * T_TOKENS) {
                token_list[slot] = token;
                slot_w[slot] = tok_w[2 * token + j];
                m = slot;
            }
        }
        map[2 * token + j] = m;
    }
}

// ============ GEMM1 packed: BM=128 BN=256 BK=32, 512 thr, ring-3 LDS,
// counted vmcnt pipeline (never drains to 0 in main loop). ============
__launch_bounds__(512, 4)
__global__ void gemm1_kernel(const unsigned short* __restrict__ xb,
                             const unsigned short* __restrict__ guwb,
                             const int* __restrict__ offs,
                             const int* __restrict__ token_list,
                             const float* __restrict__ slot_w,
                             unsigned short* __restrict__ act) {
    const int e = blockIdx.z;
    const int off = offs[e];
    int Me = offs[e + 1] - off;
    if (Me < 0) Me = 0;
    if (Me > T_TOKENS) Me = T_TOKENS;
    const int m0 = blockIdx.y * 128;
    if (m0 >= Me) return;
    const int n0 = blockIdx.x * 256;  // packed-N (2048 wide)

    __shared__ __align__(16) unsigned short As[3][128][32];
    __shared__ __align__(16) unsigned short Bs[3][256][32];

    const int tid = threadIdx.x;           // 0..511
    const int wv = tid >> 6, ln = tid & 63;  // wv 0..7
    const int sc = (ln & 3) * 8;
    const int srow = ln >> 2;              // 0..15

    // A: one gathered token row per thread (rows m0 + wv*16 + srow)
    int tr = m0 + wv * 16 + srow;
    if (tr >= Me) tr = Me - 1;
    int tok = token_list[off + tr];
    if (tok < 0 || tok >= T_TOKENS) tok = 0;
    const unsigned short* aA = xb + (size_t)tok * HDIM + sc;

    // B: packed rows n0 + wv*16 + srow and +128
    const unsigned short* aB0 = guwb + (size_t)e * 2 * IDIM * HDIM +
                                (size_t)(n0 + wv * 16 + srow) * HDIM + sc;
    const unsigned short* aB1 = aB0 + (size_t)128 * HDIM;

    const int wm = wv & 1, wn = wv >> 1;   // 2M x 4N wave grid
    const int fr = ln & 15;
    const int fk = (ln >> 4) * 8;

    f32x4_t acc[4][4] = {};

    auto STAGE = [&](int kt, int b) {
        const int k0 = kt * 32;
        async16(aA + k0, &As[b][wv * 16][0]);
        async16(aB0 + k0, &Bs[b][wv * 16][0]);
        async16(aB1 + k0, &Bs[b][128 + wv * 16][0]);
    };
    auto COMPUTE = [&](int b) {
        bf16x8_t af[4], bfr[4];
#pragma unroll
        for (int t = 0; t < 4; ++t) {
            af[t] = *(const bf16x8_t*)&As[b][wm * 64 + t * 16 + fr][fk];
            bfr[t] = *(const bf16x8_t*)&Bs[b][wn * 64 + t * 16 + fr][fk];
        }
        __builtin_amdgcn_s_setprio(1);
#pragma unroll
        for (int mt = 0; mt < 4; ++mt)
#pragma unroll
            for (int nt = 0; nt < 4; ++nt)
                acc[mt][nt] = __builtin_amdgcn_mfma_f32_16x16x32_bf16(af[mt], bfr[nt], acc[mt][nt], 0, 0, 0);
        __builtin_amdgcn_s_setprio(0);
    };

    const int NT = HDIM / 32;  // 64
    STAGE(0, 0);
    STAGE(1, 1);
    int cur = 0, nb = 2;
    for (int t = 0; t < NT - 2; ++t) {
        STAGE(t + 2, nb);
        WAITV(6);                         // tiles t+1,t+2 stay in flight
        __builtin_amdgcn_s_barrier();
        CFENCE;
        COMPUTE(cur);
        CFENCE;
        __builtin_amdgcn_s_barrier();     // reads done before buf reuse next iter
        if (++cur == 3) cur = 0;
        if (++nb == 3) nb = 0;
    }
    // tile NT-2
    WAITV(3);
    __builtin_amdgcn_s_barrier();
    CFENCE;
    COMPUTE(cur);
    CFENCE;
    __builtin_amdgcn_s_barrier();
    if (++cur == 3) cur = 0;
    // tile NT-1
    WAITV(0);
    __builtin_amdgcn_s_barrier();
    CFENCE;
    COMPUTE(cur);

    // Epilogue: packed col p = n0 + wn*64 + nt*16 + fr; (gate,up) pair lane-local:
    // i = n0/2 + wn*32 + (nt>>1)*16 + fr
    const int ibase = (n0 >> 1) + wn * 32;
#pragma unroll
    for (int mt = 0; mt < 4; ++mt) {
#pragma unroll
        for (int r = 0; r < 4; ++r) {
            int rloc = wm * 64 + mt * 16 + (ln >> 4) * 4 + r;
            int grow = m0 + rloc;
            if (grow < Me) {
                float w = slot_w[off + grow];
                size_t rb = (size_t)(off + grow) * IDIM + ibase;
#pragma unroll
                for (int t = 0; t < 2; ++t) {
                    float g = acc[mt][2 * t][r];
                    float u = acc[mt][2 * t + 1][r];
                    float s = g / (1.f + __expf(-g));
                    act[rb + t * 16 + fr] = f2bf(s * u * w);
                }
            }
        }
    }
}

// ============ GEMM2: BM=128 BN=256 BK=32, ring-3 counted-vmcnt pipeline ============
__launch_bounds__(512, 4)
__global__ void gemm2_kernel(const unsigned short* __restrict__ act,
                             const unsigned short* __restrict__ dwb,
                             const int* __restrict__ offs,
                             unsigned short* __restrict__ dout) {
    const int e = blockIdx.z;
    const int off = offs[e];
    int Me = offs[e + 1] - off;
    if (Me < 0) Me = 0;
    if (Me > T_TOKENS) Me = T_TOKENS;
    const int m0 = blockIdx.y * 128;
    if (m0 >= Me) return;
    const int n0 = blockIdx.x * 256;

    __shared__ __align__(16) unsigned short As[3][128][32];
    __shared__ __align__(16) unsigned short Bs[3][256][32];

    const int tid = threadIdx.x;
    const int wv = tid >> 6, ln = tid & 63;
    const int sc = (ln & 3) * 8;
    const int srow = ln >> 2;

    int ar = off + m0 + wv * 16 + srow;
    if (ar >= MAX_SLOTS) ar = MAX_SLOTS - 1;
    const unsigned short* aA = act + (size_t)ar * IDIM + sc;

    const unsigned short* aB0 = dwb + (size_t)e * HDIM * IDIM +
                                (size_t)(n0 + wv * 16 + srow) * IDIM + sc;
    const unsigned short* aB1 = aB0 + (size_t)128 * IDIM;

    const int wm = wv & 1, wn = wv >> 1;
    const int fr = ln & 15;
    const int fk = (ln >> 4) * 8;

    f32x4_t acc[4][4] = {};

    auto STAGE = [&](int kt, int b) {
        const int k0 = kt * 32;
        async16(aA + k0, &As[b][wv * 16][0]);
        async16(aB0 + k0, &Bs[b][wv * 16][0]);
        async16(aB1 + k0, &Bs[b][128 + wv * 16][0]);
    };
    auto COMPUTE = [&](int b) {
        bf16x8_t af[4], bfr[4];
#pragma unroll
        for (int t = 0; t < 4; ++t) {
            af[t] = *(const bf16x8_t*)&As[b][wm * 64 + t * 16 + fr][fk];
            bfr[t] = *(const bf16x8_t*)&Bs[b][wn * 64 + t * 16 + fr][fk];
        }
        __builtin_amdgcn_s_setprio(1);
#pragma unroll
        for (int mt = 0; mt < 4; ++mt)
#pragma unroll
            for (int nt = 0; nt < 4; ++nt)
                acc[mt][nt] = __builtin_amdgcn_mfma_f32_16x16x32_bf16(af[mt], bfr[nt], acc[mt][nt], 0, 0, 0);
        __builtin_amdgcn_s_setprio(0);
    };

    const int NT = IDIM / 32;  // 32
    STAGE(0, 0);
    STAGE(1, 1);
    int cur = 0, nb = 2;
    for (int t = 0; t < NT - 2; ++t) {
        STAGE(t + 2, nb);
        WAITV(6);
        __builtin_amdgcn_s_barrier();
        CFENCE;
        COMPUTE(cur);
        CFENCE;
        __builtin_amdgcn_s_barrier();
        if (++cur == 3) cur = 0;
        if (++nb == 3) nb = 0;
    }
    WAITV(3);
    __builtin_amdgcn_s_barrier();
    CFENCE;
    COMPUTE(cur);
    CFENCE;
    __builtin_amdgcn_s_barrier();
    if (++cur == 3) cur = 0;
    WAITV(0);
    __builtin_amdgcn_s_barrier();
    CFENCE;
    COMPUTE(cur);

#pragma unroll
    for (int mt = 0; mt < 4; ++mt) {
#pragma unroll
        for (int r = 0; r < 4; ++r) {
            int rloc = wm * 64 + mt * 16 + (ln >> 4) * 4 + r;
            int grow = m0 + rloc;
            if (grow < Me) {
                size_t rb = (size_t)(off + grow) * HDIM + n0;
#pragma unroll
                for (int nt = 0; nt < 4; ++nt)
                    dout[rb + wn * 64 + nt * 16 + fr] = f2bf(acc[mt][nt][r]);
            }
        }
    }
}

// ---------------- FALLBACK GEMMs (fp32 weights, cvt16 staging) ----------------
__launch_bounds__(256, 2)
__global__ void gemm1_fb(const float* __restrict__ x,
                         const float* __restrict__ gate_w,
                         const float* __restrict__ up_w,
                         const int* __restrict__ offs,
                         const int* __restrict__ token_list,
                         const float* __restrict__ slot_w,
                         unsigned short* __restrict__ act) {
    const int e = blockIdx.z;
    const int off = offs[e];
    int Me = offs[e + 1] - off;
    if (Me < 0) Me = 0;
    if (Me > T_TOKENS) Me = T_TOKENS;
    const int m0 = blockIdx.y * 128;
    if (m0 >= Me) return;
    const int n0 = blockIdx.x * 128;

    __shared__ __align__(16) unsigned short As[128][32];
    __shared__ __align__(16) unsigned short Gs[128][32];
    __shared__ __align__(16) unsigned short Us[128][32];

    const int tid = threadIdx.x;
    const int srow = tid >> 1;
    const int shalf = (tid & 1) * 16;

    int tr = m0 + srow; if (tr >= Me) tr = Me - 1;
    int tok = token_list[off + tr];
    if (tok < 0 || tok >= T_TOKENS) tok = 0;
    const float* aA = x + (size_t)tok * HDIM + shalf;
    const float* aG = gate_w + (size_t)e * IDIM * HDIM + (size_t)(n0 + srow) * HDIM + shalf;
    const float* aU = up_w + (size_t)e * IDIM * HDIM + (size_t)(n0 + srow) * HDIM + shalf;
    unsigned short* lA = &As[srow][shalf];
    unsigned short* lG = &Gs[srow][shalf];
    unsigned short* lU = &Us[srow][shalf];

    const int wv = tid >> 6, ln = tid & 63;
    const int wm = wv & 1, wn = wv >> 1;
    const int fr = ln & 15;
    const int fk = (ln >> 4) * 8;

    f32x4_t accg[4][4] = {};
    f32x4_t accu[4][4] = {};

    for (int k0 = 0; k0 < HDIM; k0 += 32) {
        cvt16(aA + k0, lA);
        cvt16(aG + k0, lG);
        cvt16(aU + k0, lU);
        __syncthreads();
        bf16x8_t af[4], gf[4], uf[4];
#pragma unroll
        for (int t = 0; t < 4; ++t) {
            af[t] = *(const bf16x8_t*)&As[wm * 64 + t * 16 + fr][fk];
            gf[t] = *(const bf16x8_t*)&Gs[wn * 64 + t * 16 + fr][fk];
            uf[t] = *(const bf16x8_t*)&Us[wn * 64 + t * 16 + fr][fk];
        }
#pragma unroll
        for (int mt = 0; mt < 4; ++mt)
#pragma unroll
            for (int nt = 0; nt < 4; ++nt) {
                accg[mt][nt] = __builtin_amdgcn_mfma_f32_16x16x32_bf16(af[mt], gf[nt], accg[mt][nt], 0, 0, 0);
                accu[mt][nt] = __builtin_amdgcn_mfma_f32_16x16x32_bf16(af[mt], uf[nt], accu[mt][nt], 0, 0, 0);
            }
        __syncthreads();
    }

#pragma unroll
    for (int mt = 0; mt < 4; ++mt) {
#pragma unroll
        for (int r = 0; r < 4; ++r) {
            int rloc = wm * 64 + mt * 16 + (ln >> 4) * 4 + r;
            int grow = m0 + rloc;
            if (grow < Me) {
                float w = slot_w[off + grow];
                size_t rb = (size_t)(off + grow) * IDIM + n0;
#pragma unroll
                for (int nt = 0; nt < 4; ++nt) {
                    float g = accg[mt][nt][r];
                    float u = accu[mt][nt][r];
                    float s = g / (1.f + __expf(-g));
                    act[rb + wn * 64 + nt * 16 + fr] = f2bf(s * u * w);
                }
            }
        }
    }
}

__launch_bounds__(256, 2)
__global__ void gemm2_fb(const unsigned short* __restrict__ act,
                         const float* __restrict__ dwn,
                         const int* __restrict__ offs,
                         unsigned short* __restrict__ dout) {
    const int e = blockIdx.z;
    const int off = offs[e];
    int Me = offs[e + 1] - off;
    if (Me < 0) Me = 0;
    if (Me > T_TOKENS) Me = T_TOKENS;
    const int m0 = blockIdx.y * 128;
    if (m0 >= Me) return;
    const int n0 = blockIdx.x * 128;

    __shared__ __align__(16) unsigned short As[128][32];
    __shared__ __align__(16) unsigned short Bs[128][32];

    const int tid = threadIdx.x;
    const int wv = tid >> 6, ln = tid & 63;

    const int sr0 = wv * 16 + (ln >> 2);
    const int sc = (ln & 3) * 8;
    int ar0 = off + m0 + sr0;      if (ar0 >= MAX_SLOTS) ar0 = MAX_SLOTS - 1;
    int ar1 = off + m0 + 64 + sr0; if (ar1 >= MAX_SLOTS) ar1 = MAX_SLOTS - 1;
    const unsigned short* aA0 = act + (size_t)ar0 * IDIM + sc;
    const unsigned short* aA1 = act + (size_t)ar1 * IDIM + sc;
    unsigned short* lA0 = &As[wv * 16][0];
    unsigned short* lA1 = &As[64 + wv * 16][0];

    const int srow = tid >> 1;
    const int shalf = (tid & 1) * 16;
    const float* aB = dwn + (size_t)e * HDIM * IDIM + (size_t)(n0 + srow) * IDIM + shalf;
    unsigned short* lB = &Bs[srow][shalf];

    const int wm = wv & 1, wn = wv >> 1;
    const int fr = ln & 15;
    const int fk = (ln >> 4) * 8;

    f32x4_t acc[4][4] = {};

    for (int k0 = 0; k0 < IDIM; k0 += 32) {
        async16(aA0 + k0, lA0);
        async16(aA1 + k0, lA1);
        cvt16(aB + k0, lB);
        __syncthreads();
        bf16x8_t af[4], bfr[4];
#pragma unroll
        for (int t = 0; t < 4; ++t) {
            af[t] = *(const bf16x8_t*)&As[wm * 64 + t * 16 + fr][fk];
            bfr[t] = *(const bf16x8_t*)&Bs[wn * 64 + t * 16 + fr][fk];
        }
#pragma unroll
        for (int mt = 0; mt < 4; ++mt)
#pragma unroll
            for (int nt = 0; nt < 4; ++nt)
                acc[mt][nt] = __builtin_amdgcn_mfma_f32_16x16x32_bf16(af[mt], bfr[nt], acc[mt][nt], 0, 0, 0);
        __syncthreads();
    }

#pragma unroll
    for (int mt = 0; mt < 4; ++mt) {
#pragma unroll
        for (int r = 0; r < 4; ++r) {
            int rloc = wm * 64 + mt * 16 + (ln >> 4) * 4 + r;
            int grow = m0 + rloc;
            if (grow < Me) {
                size_t rb = (size_t)(off + grow) * HDIM + n0;
#pragma unroll
                for (int nt = 0; nt < 4; ++nt)
                    dout[rb + wn * 64 + nt * 16 + fr] = f2bf(acc[mt][nt][r]);
            }
        }
    }
}

// ---------------- finalize: out(fp32) = sum(slot rows bf16) + zero_w * x(fp32) ----------------
__global__ void finalize_kernel(const float* __restrict__ x,
                                const unsigned short* __restrict__ dout,
                                const int* __restrict__ map,
                                const float* __restrict__ zero_w,
                                float* __restrict__ out) {
    int gid = blockIdx.x * blockDim.x + threadIdx.x;  // T*H/8 total
    int token = gid >> 8;
    int hg = (gid & 255) * 8;
    int s0 = map[2 * token], s1 = map[2 * token + 1];
    float zw = zero_w[token];
    size_t base = (size_t)token * HDIM + hg;
    f32x4_t x0 = *(const f32x4_t*)(x + base);
    f32x4_t x1 = *(const f32x4_t*)(x + base + 4);
    float o[8];
#pragma unroll
    for (int j = 0; j < 4; ++j) { o[j] = zw * x0[j]; o[4 + j] = zw * x1[j]; }
    if (s0 >= 0 && s0 < 2 * T_TOKENS) {
        u16x8_t d = *(const u16x8_t*)(dout + (size_t)s0 * HDIM + hg);
#pragma unroll
        for (int j = 0; j < 8; ++j) o[j] += bfu2f(d[j]);
    }
    if (s1 >= 0 && s1 < 2 * T_TOKENS) {
        u16x8_t d = *(const u16x8_t*)(dout + (size_t)s1 * HDIM + hg);
#pragma unroll
        for (int j = 0; j < 8; ++j) o[j] += bfu2f(d[j]);
    }
    f32x4_t o0, o1;
#pragma unroll
    for (int j = 0; j < 4; ++j) { o0[j] = o[j]; o1[j] = o[4 + j]; }
    *(f32x4_t*)(out + base) = o0;
    *(f32x4_t*)(out + base + 4) = o1;
}

// ---------------- launch ----------------
extern "C" void kernel_launch(void* const* d_in, const int* in_sizes, int n_in,
                              void* d_out, int out_size, void* d_ws, size_t ws_size,
                              hipStream_t stream) {
    const float* x = (const float*)d_in[0];
    const float* cw = (const float*)d_in[1];
    const float* bias = (const float*)d_in[2];
    const float* gw = (const float*)d_in[3];
    const float* uw = (const float*)d_in[4];
    const float* dw = (const float*)d_in[5];
    float* out = (float*)d_out;

    char* ws = (char*)d_ws;
    int* counts = (int*)(ws + 0);                 // 32 B
    int* fill = (int*)(ws + 32);                  // 32 B
    int* offs = (int*)(ws + 64);                  // 64 B (9 ints)
    int* tok_e = (int*)(ws + 128);                // 32768
    float* tok_w = (float*)(ws + 32896);          // 32768
    float* zero_w = (float*)(ws + 65664);         // 16384
    int* map = (int*)(ws + 82048);                // 32768
    int* token_list = (int*)(ws + 114816);        // 33280
    float* slot_w = (float*)(ws + 148096);        // 33280
    unsigned short* act = (unsigned short*)(ws + 181504);              // 8320*1024*2
    unsigned short* dout = (unsigned short*)(ws + 17220864);           // 8320*2048*2
    const size_t needed_small = 51299584ull;
    // bf16 buffers for the fast path
    unsigned short* xb   = (unsigned short*)(ws + 51299584ull);   // 4096*2048*2   = 16 MB
    unsigned short* guwb = (unsigned short*)(ws + 68076800ull);   // 8*2048*2048*2 = 64 MB (packed gate|up)
    unsigned short* dwb  = (unsigned short*)(ws + 135185664ull);  // 8*2048*1024*2 = 32 MB
    const size_t needed_big = 168740096ull;

    if (ws_size < needed_small) {
        noop_kernel<<<1, 64, 0, stream>>>();
        return;
    }

    init_kernel<<<1, 64, 0, stream>>>((int*)ws);

    if (ws_size >= needed_big) {
        router_kernel<<<T_TOKENS, 64, 0, stream>>>(x, cw, bias, counts, tok_e, tok_w, zero_w, xb);
        scan_kernel<<<1, 64, 0, stream>>>(counts, offs);
        place_kernel<<<(T_TOKENS + 255) / 256, 256, 0, stream>>>(tok_e, tok_w, offs, fill,
                                                                 token_list, slot_w, map);
        pack_w_kernel<<<4096, 256, 0, stream>>>(gw, uw, dw, guwb, dwb);
        gemm1_kernel<<<dim3(2 * IDIM / 256, 32, NEXP), 512, 0, stream>>>(xb, guwb, offs,
                                                                         token_list, slot_w, act);
        gemm2_kernel<<<dim3(HDIM / 256, 32, NEXP), 512, 0, stream>>>(act, dwb, offs, dout);
    } else {
        router_kernel<<<T_TOKENS, 64, 0, stream>>>(x, cw, bias, counts, tok_e, tok_w, zero_w,
                                                   (unsigned short*)nullptr);
        scan_kernel<<<1, 64, 0, stream>>>(counts, offs);
        place_kernel<<<(T_TOKENS + 255) / 256, 256, 0, stream>>>(tok_e, tok_w, offs, fill,
                                                                 token_list, slot_w, map);
        gemm1_fb<<<dim3(IDIM / 128, 32, NEXP), 256, 0, stream>>>(x, gw, uw, offs,
                                                                 token_list, slot_w, act);
        gemm2_fb<<<dim3(HDIM / 128, 32, NEXP), 256, 0, stream>>>(act, dw, offs, dout);
    }

    finalize_kernel<<<(T_TOKENS * HDIM / 8 + 255) / 256, 256, 0, stream>>>(x, dout, map,
                                                                           zero_w, out);
}

// Round 5
// 519.187 us; speedup vs baseline: 1.0062x; 1.0062x over previous
//
#include <hip/hip_runtime.h>
#include <cstdint>

#define T_TOKENS 4096
#define HDIM 2048
#define IDIM 1024
#define NEXP 8
#define NTOT 12
#define MAX_SLOTS 8320   // 8192 + 128 pad for tile overshoot reads

typedef __bf16 bf16x8_t __attribute__((ext_vector_type(8)));
typedef float f32x4_t __attribute__((ext_vector_type(4)));
typedef unsigned short u16x8_t __attribute__((ext_vector_type(8)));
typedef unsigned short u16x4_t __attribute__((ext_vector_type(4)));

__device__ __forceinline__ unsigned short f2bf(float f) {
    unsigned int u = __builtin_bit_cast(unsigned int, f);
    u += 0x7fffu + ((u >> 16) & 1u);
    return (unsigned short)(u >> 16);
}
__device__ __forceinline__ float bfu2f(unsigned short u) {
    unsigned int v = ((unsigned int)u) << 16;
    return __builtin_bit_cast(float, v);
}
// async global->LDS, 16B per lane; LDS dest = wave-uniform base + lane*16
__device__ __forceinline__ void async16(const unsigned short* g, unsigned short* l) {
    __builtin_amdgcn_global_load_lds(
        (const unsigned int __attribute__((address_space(1)))*)g,
        (unsigned int __attribute__((address_space(3)))*)l,
        16, 0, 0);
}
// read 16 fp32, convert RNE to bf16, write 32B to LDS (fallback path only)
__device__ __forceinline__ void cvt16(const float* src, unsigned short* dst) {
    f32x4_t f0 = ((const f32x4_t*)src)[0];
    f32x4_t f1 = ((const f32x4_t*)src)[1];
    f32x4_t f2 = ((const f32x4_t*)src)[2];
    f32x4_t f3 = ((const f32x4_t*)src)[3];
    u16x8_t a, b;
#pragma unroll
    for (int j = 0; j < 4; ++j) { a[j] = f2bf(f0[j]); a[4 + j] = f2bf(f1[j]); }
#pragma unroll
    for (int j = 0; j < 4; ++j) { b[j] = f2bf(f2[j]); b[4 + j] = f2bf(f3[j]); }
    ((u16x8_t*)dst)[0] = a;
    ((u16x8_t*)dst)[1] = b;
}

// ---------------- zero-init metadata ----------------
__global__ void init_kernel(int* __restrict__ meta) {
    int i = threadIdx.x;
    if (i < 32) meta[i] = 0;
}

__global__ void noop_kernel() {}

// ---------------- pure streaming fp32->bf16 convert of gw, uw, dw ----------------
// Each array is 8*1024*2048 = 16777216 floats = 2^21 groups of 8.
__global__ void cvt3_kernel(const float* __restrict__ gw, const float* __restrict__ uw,
                            const float* __restrict__ dw,
                            unsigned short* __restrict__ gwb, unsigned short* __restrict__ uwb,
                            unsigned short* __restrict__ dwb) {
    const int n8 = 3 * (1 << 21);  // 6291456
    int stride = gridDim.x * blockDim.x;
    for (int i = blockIdx.x * blockDim.x + threadIdx.x; i < n8; i += stride) {
        int seg = i >> 21;
        int k = i & ((1 << 21) - 1);
        const float* s = (seg == 0) ? gw : (seg == 1) ? uw : dw;
        unsigned short* d = (seg == 0) ? gwb : (seg == 1) ? uwb : dwb;
        const f32x4_t* p = (const f32x4_t*)(s + (size_t)k * 8);
        f32x4_t a = p[0], b = p[1];
        u16x8_t o;
#pragma unroll
        for (int j = 0; j < 4; ++j) { o[j] = f2bf(a[j]); o[4 + j] = f2bf(b[j]); }
        ((u16x8_t*)d)[k] = o;
    }
}

// ---------------- Router (fp32): logits->softmax->top2; also emits bf16 x ----------------
__global__ void router_kernel(const float* __restrict__ x,
                              const float* __restrict__ cw,
                              const float* __restrict__ bias,
                              int* __restrict__ counts,
                              int* __restrict__ tok_e,
                              float* __restrict__ tok_w,
                              float* __restrict__ zero_w,
                              unsigned short* __restrict__ xb) {
    const int token = blockIdx.x;
    const int ln = threadIdx.x;  // 0..63
    const float* xr = x + (size_t)token * HDIM;
    float acc[NTOT];
#pragma unroll
    for (int e = 0; e < NTOT; ++e) acc[e] = 0.f;
    for (int h0 = ln * 4; h0 < HDIM; h0 += 256) {
        f32x4_t xv = *(const f32x4_t*)(xr + h0);
        if (xb) {
            u16x4_t o;
#pragma unroll
            for (int j = 0; j < 4; ++j) o[j] = f2bf(xv[j]);
            *(u16x4_t*)(xb + (size_t)token * HDIM + h0) = o;
        }
#pragma unroll
        for (int e = 0; e < NTOT; ++e) {
            f32x4_t wv = *(const f32x4_t*)(cw + e * HDIM + h0);
            acc[e] += xv[0] * wv[0] + xv[1] * wv[1] + xv[2] * wv[2] + xv[3] * wv[3];
        }
    }
#pragma unroll
    for (int e = 0; e < NTOT; ++e) {
        float v = acc[e];
#pragma unroll
        for (int s = 32; s > 0; s >>= 1) v += __shfl_xor(v, s, 64);
        acc[e] = v;
    }
    if (ln == 0) {
        float mx = acc[0];
#pragma unroll
        for (int e = 1; e < NTOT; ++e) mx = fmaxf(mx, acc[e]);
        float p[NTOT];
        float sum = 0.f;
#pragma unroll
        for (int e = 0; e < NTOT; ++e) { p[e] = __expf(acc[e] - mx); sum += p[e]; }
        float inv = 1.f / sum;
#pragma unroll
        for (int e = 0; e < NTOT; ++e) p[e] *= inv;
        float b[NTOT];
#pragma unroll
        for (int e = 0; e < NTOT; ++e) b[e] = p[e] + bias[e];
        int i0 = 0; float v0 = b[0];
#pragma unroll
        for (int e = 1; e < NTOT; ++e) if (b[e] > v0) { v0 = b[e]; i0 = e; }
        int i1 = -1; float v1 = -3.0e38f;
#pragma unroll
        for (int e = 0; e < NTOT; ++e) if (e != i0 && b[e] > v1) { v1 = b[e]; i1 = e; }
        if (i1 < 0) i1 = (i0 == 0) ? 1 : 0;  // defensive
        float w0 = p[i0] * 1.5f, w1 = p[i1] * 1.5f;
        tok_e[2 * token] = i0; tok_e[2 * token + 1] = i1;
        tok_w[2 * token] = w0; tok_w[2 * token + 1] = w1;
        float zw = 0.f;
        if (i0 >= NEXP) zw += w0; else atomicAdd(&counts[i0], 1);
        if (i1 >= NEXP) zw += w1; else atomicAdd(&counts[i1], 1);
        zero_w[token] = zw;
    }
}

// ---------------- prefix scan over 8 experts ----------------
__global__ void scan_kernel(const int* __restrict__ counts, int* __restrict__ offs) {
    if (threadIdx.x == 0 && blockIdx.x == 0) {
        int a = 0;
        for (int e = 0; e < NEXP; ++e) {
            offs[e] = a;
            int c = counts[e];
            if (c < 0) c = 0;
            if (c > T_TOKENS) c = T_TOKENS;
            a += c;
        }
        if (a > 2 * T_TOKENS) a = 2 * T_TOKENS;
        offs[NEXP] = a;
    }
}

// ---------------- place tokens into per-expert contiguous lists ----------------
__global__ void place_kernel(const int* __restrict__ tok_e, const float* __restrict__ tok_w,
                             const int* __restrict__ offs, int* __restrict__ fill,
                             int* __restrict__ token_list, float* __restrict__ slot_w,
                             int* __restrict__ map) {
    int token = blockIdx.x * blockDim.x + threadIdx.x;
    if (token >= T_TOKENS) return;
#pragma unroll
    for (int j = 0; j < 2; ++j) {
        int e = tok_e[2 * token + j];
        int m = -1;
        if (e >= 0 && e < NEXP) {
            int pos = atomicAdd(&fill[e], 1);
            int slot = offs[e] + pos;
            if (slot >= 0 && slot < 2 * T_TOKENS) {
                token_list[slot] = token;
                slot_w[slot] = tok_w[2 * token + j];
                m = slot;
            }
        }
        map[2 * token + j] = m;
    }
}

// ---------------- preout: out = zero_w * x ----------------
__global__ void preout_kernel(const float* __restrict__ x, const float* __restrict__ zero_w,
                              float* __restrict__ out) {
    int gid = blockIdx.x * blockDim.x + threadIdx.x;  // T*H/8 total
    int token = gid >> 8;
    int hg = (gid & 255) * 8;
    float zw = zero_w[token];
    size_t base = (size_t)token * HDIM + hg;
    f32x4_t x0 = *(const f32x4_t*)(x + base);
    f32x4_t x1 = *(const f32x4_t*)(x + base + 4);
    f32x4_t o0, o1;
#pragma unroll
    for (int j = 0; j < 4; ++j) { o0[j] = zw * x0[j]; o1[j] = zw * x1[j]; }
    *(f32x4_t*)(out + base) = o0;
    *(f32x4_t*)(out + base + 4) = o1;
}

// ============ GEMM1: bf16 all-async, 128x128packed tile, stage-time gate/up interleave.
// LDS B layout == packed guwb layout of earlier rounds: row p (j=p>>5, r=p&31):
// r<16 -> gate[16j+r], else up[16j+r-16]. Built here from PLAIN gwb/uwb by chunk parity.
__launch_bounds__(256, 3)
__global__ void gemm1_kernel(const unsigned short* __restrict__ xb,
                             const unsigned short* __restrict__ gwb,
                             const unsigned short* __restrict__ uwb,
                             const int* __restrict__ offs,
                             const int* __restrict__ token_list,
                             const float* __restrict__ slot_w,
                             unsigned short* __restrict__ act) {
    const int e = blockIdx.z;
    const int off = offs[e];
    int Me = offs[e + 1] - off;
    if (Me < 0) Me = 0;
    if (Me > T_TOKENS) Me = T_TOKENS;
    const int m0 = blockIdx.y * 128;
    if (m0 >= Me) return;
    const int n0 = blockIdx.x * 128;  // packed-N (2048 wide)

    __shared__ __align__(16) unsigned short As[128][32];
    __shared__ __align__(16) unsigned short Bs[128][32];

    const int tid = threadIdx.x;
    const int wv = tid >> 6, ln = tid & 63;
    const int sc = (ln & 3) * 8;
    const int R = ln >> 2;

    // A staging: wave wv stages rows [wv*16, +16) and +64 (gathered tokens)
    int tr0 = m0 + wv * 16 + R;      if (tr0 >= Me) tr0 = Me - 1;
    int tr1 = m0 + 64 + wv * 16 + R; if (tr1 >= Me) tr1 = Me - 1;
    int tok0 = token_list[off + tr0]; if (tok0 < 0 || tok0 >= T_TOKENS) tok0 = 0;
    int tok1 = token_list[off + tr1]; if (tok1 < 0 || tok1 >= T_TOKENS) tok1 = 0;
    const unsigned short* aA0 = xb + (size_t)tok0 * HDIM + sc;
    const unsigned short* aA1 = xb + (size_t)tok1 * HDIM + sc;
    unsigned short* lA0 = &As[wv * 16][0];
    unsigned short* lA1 = &As[64 + wv * 16][0];

    // B staging with stage-time interleave: chunk c=wv -> Bs rows [wv*16,+16),
    // chunk c=wv+4 -> +64. Even chunk -> gate, odd -> up; both at intermediate
    // row base (n0/2) + (wv>>1)*16 (+32 for the second chunk).
    const unsigned short* wsel = (wv & 1) ? uwb : gwb;
    const unsigned short* aB0 = wsel + (size_t)e * IDIM * HDIM +
                                (size_t)((n0 >> 1) + (wv >> 1) * 16 + R) * HDIM + sc;
    const unsigned short* aB1 = aB0 + (size_t)32 * HDIM;
    unsigned short* lB0 = &Bs[wv * 16][0];
    unsigned short* lB1 = &Bs[64 + wv * 16][0];

    const int wm = wv & 1, wn = wv >> 1;
    const int fr = ln & 15;
    const int fk = (ln >> 4) * 8;

    f32x4_t acc[4][4] = {};

    for (int k0 = 0; k0 < HDIM; k0 += 32) {
        async16(aA0 + k0, lA0);
        async16(aA1 + k0, lA1);
        async16(aB0 + k0, lB0);
        async16(aB1 + k0, lB1);
        __syncthreads();
        bf16x8_t af[4], bfr[4];
#pragma unroll
        for (int t = 0; t < 4; ++t) {
            af[t] = *(const bf16x8_t*)&As[wm * 64 + t * 16 + fr][fk];
            bfr[t] = *(const bf16x8_t*)&Bs[wn * 64 + t * 16 + fr][fk];
        }
#pragma unroll
        for (int mt = 0; mt < 4; ++mt)
#pragma unroll
            for (int nt = 0; nt < 4; ++nt)
                acc[mt][nt] = __builtin_amdgcn_mfma_f32_16x16x32_bf16(af[mt], bfr[nt], acc[mt][nt], 0, 0, 0);
        __syncthreads();
    }

    // Epilogue: packed col p = n0 + wn*64 + nt*16 + fr.
    // nt even -> gate of intermediate i; nt odd -> up of the SAME i,
    // i = n0/2 + wn*32 + (nt>>1)*16 + fr  (lane-local pairing).
    const int ibase = (n0 >> 1) + wn * 32;
#pragma unroll
    for (int mt = 0; mt < 4; ++mt) {
#pragma unroll
        for (int r = 0; r < 4; ++r) {
            int rloc = wm * 64 + mt * 16 + (ln >> 4) * 4 + r;
            int grow = m0 + rloc;
            if (grow < Me) {
                float w = slot_w[off + grow];
                size_t rb = (size_t)(off + grow) * IDIM + ibase;
#pragma unroll
                for (int t = 0; t < 2; ++t) {
                    float g = acc[mt][2 * t][r];
                    float u = acc[mt][2 * t + 1][r];
                    float s = g / (1.f + __expf(-g));
                    act[rb + t * 16 + fr] = f2bf(s * u * w);
                }
            }
        }
    }
}

// ============ GEMM2: bf16 all-async; epilogue atomically accumulates fp32 into out ============
__launch_bounds__(256, 3)
__global__ void gemm2_kernel(const unsigned short* __restrict__ act,
                             const unsigned short* __restrict__ dwb,
                             const int* __restrict__ offs,
                             const int* __restrict__ token_list,
                             float* __restrict__ out) {
    const int e = blockIdx.z;
    const int off = offs[e];
    int Me = offs[e + 1] - off;
    if (Me < 0) Me = 0;
    if (Me > T_TOKENS) Me = T_TOKENS;
    const int m0 = blockIdx.y * 128;
    if (m0 >= Me) return;
    const int n0 = blockIdx.x * 128;

    __shared__ __align__(16) unsigned short As[128][32];
    __shared__ __align__(16) unsigned short Bs[128][32];

    const int tid = threadIdx.x;
    const int wv = tid >> 6, ln = tid & 63;
    const int sc = (ln & 3) * 8;
    const int R = ln >> 2;

    // A staging: wave wv stages rows [wv*16, +16) and +64
    int ar0 = off + m0 + wv * 16 + R;      if (ar0 >= MAX_SLOTS) ar0 = MAX_SLOTS - 1;
    int ar1 = off + m0 + 64 + wv * 16 + R; if (ar1 >= MAX_SLOTS) ar1 = MAX_SLOTS - 1;
    const unsigned short* aA0 = act + (size_t)ar0 * IDIM + sc;
    const unsigned short* aA1 = act + (size_t)ar1 * IDIM + sc;
    unsigned short* lA0 = &As[wv * 16][0];
    unsigned short* lA1 = &As[64 + wv * 16][0];

    // B staging: rows [n0 + wv*16, +16) and +64
    const unsigned short* aB0 = dwb + (size_t)e * HDIM * IDIM +
                                (size_t)(n0 + wv * 16 + R) * IDIM + sc;
    const unsigned short* aB1 = aB0 + (size_t)64 * IDIM;
    unsigned short* lB0 = &Bs[wv * 16][0];
    unsigned short* lB1 = &Bs[64 + wv * 16][0];

    const int wm = wv & 1, wn = wv >> 1;
    const int fr = ln & 15;
    const int fk = (ln >> 4) * 8;

    f32x4_t acc[4][4] = {};

    for (int k0 = 0; k0 < IDIM; k0 += 32) {
        async16(aA0 + k0, lA0);
        async16(aA1 + k0, lA1);
        async16(aB0 + k0, lB0);
        async16(aB1 + k0, lB1);
        __syncthreads();
        bf16x8_t af[4], bfr[4];
#pragma unroll
        for (int t = 0; t < 4; ++t) {
            af[t] = *(const bf16x8_t*)&As[wm * 64 + t * 16 + fr][fk];
            bfr[t] = *(const bf16x8_t*)&Bs[wn * 64 + t * 16 + fr][fk];
        }
#pragma unroll
        for (int mt = 0; mt < 4; ++mt)
#pragma unroll
            for (int nt = 0; nt < 4; ++nt)
                acc[mt][nt] = __builtin_amdgcn_mfma_f32_16x16x32_bf16(af[mt], bfr[nt], acc[mt][nt], 0, 0, 0);
        __syncthreads();
    }

#pragma unroll
    for (int mt = 0; mt < 4; ++mt) {
#pragma unroll
        for (int r = 0; r < 4; ++r) {
            int rloc = wm * 64 + mt * 16 + (ln >> 4) * 4 + r;
            int grow = m0 + rloc;
            if (grow < Me) {
                int tokr = token_list[off + grow];
                if (tokr >= 0 && tokr < T_TOKENS) {
                    size_t rb = (size_t)tokr * HDIM + n0;
#pragma unroll
                    for (int nt = 0; nt < 4; ++nt)
                        atomicAdd(&out[rb + wn * 64 + nt * 16 + fr], acc[mt][nt][r]);
                }
            }
        }
    }
}

// ---------------- FALLBACK GEMMs (fp32 weights, cvt16 staging) ----------------
__launch_bounds__(256, 2)
__global__ void gemm1_fb(const float* __restrict__ x,
                         const float* __restrict__ gate_w,
                         const float* __restrict__ up_w,
                         const int* __restrict__ offs,
                         const int* __restrict__ token_list,
                         const float* __restrict__ slot_w,
                         unsigned short* __restrict__ act) {
    const int e = blockIdx.z;
    const int off = offs[e];
    int Me = offs[e + 1] - off;
    if (Me < 0) Me = 0;
    if (Me > T_TOKENS) Me = T_TOKENS;
    const int m0 = blockIdx.y * 128;
    if (m0 >= Me) return;
    const int n0 = blockIdx.x * 128;

    __shared__ __align__(16) unsigned short As[128][32];
    __shared__ __align__(16) unsigned short Gs[128][32];
    __shared__ __align__(16) unsigned short Us[128][32];

    const int tid = threadIdx.x;
    const int srow = tid >> 1;
    const int shalf = (tid & 1) * 16;

    int tr = m0 + srow; if (tr >= Me) tr = Me - 1;
    int tok = token_list[off + tr];
    if (tok < 0 || tok >= T_TOKENS) tok = 0;
    const float* aA = x + (size_t)tok * HDIM + shalf;
    const float* aG = gate_w + (size_t)e * IDIM * HDIM + (size_t)(n0 + srow) * HDIM + shalf;
    const float* aU = up_w + (size_t)e * IDIM * HDIM + (size_t)(n0 + srow) * HDIM + shalf;
    unsigned short* lA = &As[srow][shalf];
    unsigned short* lG = &Gs[srow][shalf];
    unsigned short* lU = &Us[srow][shalf];

    const int wv = tid >> 6, ln = tid & 63;
    const int wm = wv & 1, wn = wv >> 1;
    const int fr = ln & 15;
    const int fk = (ln >> 4) * 8;

    f32x4_t accg[4][4] = {};
    f32x4_t accu[4][4] = {};

    for (int k0 = 0; k0 < HDIM; k0 += 32) {
        cvt16(aA + k0, lA);
        cvt16(aG + k0, lG);
        cvt16(aU + k0, lU);
        __syncthreads();
        bf16x8_t af[4], gf[4], uf[4];
#pragma unroll
        for (int t = 0; t < 4; ++t) {
            af[t] = *(const bf16x8_t*)&As[wm * 64 + t * 16 + fr][fk];
            gf[t] = *(const bf16x8_t*)&Gs[wn * 64 + t * 16 + fr][fk];
            uf[t] = *(const bf16x8_t*)&Us[wn * 64 + t * 16 + fr][fk];
        }
#pragma unroll
        for (int mt = 0; mt < 4; ++mt)
#pragma unroll
            for (int nt = 0; nt < 4; ++nt) {
                accg[mt][nt] = __builtin_amdgcn_mfma_f32_16x16x32_bf16(af[mt], gf[nt], accg[mt][nt], 0, 0, 0);
                accu[mt][nt] = __builtin_amdgcn_mfma_f32_16x16x32_bf16(af[mt], uf[nt], accu[mt][nt], 0, 0, 0);
            }
        __syncthreads();
    }

#pragma unroll
    for (int mt = 0; mt < 4; ++mt) {
#pragma unroll
        for (int r = 0; r < 4; ++r) {
            int rloc = wm * 64 + mt * 16 + (ln >> 4) * 4 + r;
            int grow = m0 + rloc;
            if (grow < Me) {
                float w = slot_w[off + grow];
                size_t rb = (size_t)(off + grow) * IDIM + n0;
#pragma unroll
                for (int nt = 0; nt < 4; ++nt) {
                    float g = accg[mt][nt][r];
                    float u = accu[mt][nt][r];
                    float s = g / (1.f + __expf(-g));
                    act[rb + wn * 64 + nt * 16 + fr] = f2bf(s * u * w);
                }
            }
        }
    }
}

__launch_bounds__(256, 2)
__global__ void gemm2_fb(const unsigned short* __restrict__ act,
                         const float* __restrict__ dwn,
                         const int* __restrict__ offs,
                         unsigned short* __restrict__ dout) {
    const int e = blockIdx.z;
    const int off = offs[e];
    int Me = offs[e + 1] - off;
    if (Me < 0) Me = 0;
    if (Me > T_TOKENS) Me = T_TOKENS;
    const int m0 = blockIdx.y * 128;
    if (m0 >= Me) return;
    const int n0 = blockIdx.x * 128;

    __shared__ __align__(16) unsigned short As[128][32];
    __shared__ __align__(16) unsigned short Bs[128][32];

    const int tid = threadIdx.x;
    const int wv = tid >> 6, ln = tid & 63;

    const int sr0 = wv * 16 + (ln >> 2);
    const int sc = (ln & 3) * 8;
    int ar0 = off + m0 + sr0;      if (ar0 >= MAX_SLOTS) ar0 = MAX_SLOTS - 1;
    int ar1 = off + m0 + 64 + sr0; if (ar1 >= MAX_SLOTS) ar1 = MAX_SLOTS - 1;
    const unsigned short* aA0 = act + (size_t)ar0 * IDIM + sc;
    const unsigned short* aA1 = act + (size_t)ar1 * IDIM + sc;
    unsigned short* lA0 = &As[wv * 16][0];
    unsigned short* lA1 = &As[64 + wv * 16][0];

    const int srow = tid >> 1;
    const int shalf = (tid & 1) * 16;
    const float* aB = dwn + (size_t)e * HDIM * IDIM + (size_t)(n0 + srow) * IDIM + shalf;
    unsigned short* lB = &Bs[srow][shalf];

    const int wm = wv & 1, wn = wv >> 1;
    const int fr = ln & 15;
    const int fk = (ln >> 4) * 8;

    f32x4_t acc[4][4] = {};

    for (int k0 = 0; k0 < IDIM; k0 += 32) {
        async16(aA0 + k0, lA0);
        async16(aA1 + k0, lA1);
        cvt16(aB + k0, lB);
        __syncthreads();
        bf16x8_t af[4], bfr[4];
#pragma unroll
        for (int t = 0; t < 4; ++t) {
            af[t] = *(const bf16x8_t*)&As[wm * 64 + t * 16 + fr][fk];
            bfr[t] = *(const bf16x8_t*)&Bs[wn * 64 + t * 16 + fr][fk];
        }
#pragma unroll
        for (int mt = 0; mt < 4; ++mt)
#pragma unroll
            for (int nt = 0; nt < 4; ++nt)
                acc[mt][nt] = __builtin_amdgcn_mfma_f32_16x16x32_bf16(af[mt], bfr[nt], acc[mt][nt], 0, 0, 0);
        __syncthreads();
    }

#pragma unroll
    for (int mt = 0; mt < 4; ++mt) {
#pragma unroll
        for (int r = 0; r < 4; ++r) {
            int rloc = wm * 64 + mt * 16 + (ln >> 4) * 4 + r;
            int grow = m0 + rloc;
            if (grow < Me) {
                size_t rb = (size_t)(off + grow) * HDIM + n0;
#pragma unroll
                for (int nt = 0; nt < 4; ++nt)
                    dout[rb + wn * 64 + nt * 16 + fr] = f2bf(acc[mt][nt][r]);
            }
        }
    }
}

// ---------------- finalize (fallback only) ----------------
__global__ void finalize_kernel(const float* __restrict__ x,
                                const unsigned short* __restrict__ dout,
                                const int* __restrict__ map,
                                const float* __restrict__ zero_w,
                                float* __restrict__ out) {
    int gid = blockIdx.x * blockDim.x + threadIdx.x;  // T*H/8 total
    int token = gid >> 8;
    int hg = (gid & 255) * 8;
    int s0 = map[2 * token], s1 = map[2 * token + 1];
    float zw = zero_w[token];
    size_t base = (size_t)token * HDIM + hg;
    f32x4_t x0 = *(const f32x4_t*)(x + base);
    f32x4_t x1 = *(const f32x4_t*)(x + base + 4);
    float o[8];
#pragma unroll
    for (int j = 0; j < 4; ++j) { o[j] = zw * x0[j]; o[4 + j] = zw * x1[j]; }
    if (s0 >= 0 && s0 < 2 * T_TOKENS) {
        u16x8_t d = *(const u16x8_t*)(dout + (size_t)s0 * HDIM + hg);
#pragma unroll
        for (int j = 0; j < 8; ++j) o[j] += bfu2f(d[j]);
    }
    if (s1 >= 0 && s1 < 2 * T_TOKENS) {
        u16x8_t d = *(const u16x8_t*)(dout + (size_t)s1 * HDIM + hg);
#pragma unroll
        for (int j = 0; j < 8; ++j) o[j] += bfu2f(d[j]);
    }
    f32x4_t o0, o1;
#pragma unroll
    for (int j = 0; j < 4; ++j) { o0[j] = o[j]; o1[j] = o[4 + j]; }
    *(f32x4_t*)(out + base) = o0;
    *(f32x4_t*)(out + base + 4) = o1;
}

// ---------------- launch ----------------
extern "C" void kernel_launch(void* const* d_in, const int* in_sizes, int n_in,
                              void* d_out, int out_size, void* d_ws, size_t ws_size,
                              hipStream_t stream) {
    const float* x = (const float*)d_in[0];
    const float* cw = (const float*)d_in[1];
    const float* bias = (const float*)d_in[2];
    const float* gw = (const float*)d_in[3];
    const float* uw = (const float*)d_in[4];
    const float* dw = (const float*)d_in[5];
    float* out = (float*)d_out;

    char* ws = (char*)d_ws;
    int* counts = (int*)(ws + 0);                 // 32 B
    int* fill = (int*)(ws + 32);                  // 32 B
    int* offs = (int*)(ws + 64);                  // 64 B (9 ints)
    int* tok_e = (int*)(ws + 128);                // 32768
    float* tok_w = (float*)(ws + 32896);          // 32768
    float* zero_w = (float*)(ws + 65664);         // 16384
    int* map = (int*)(ws + 82048);                // 32768
    int* token_list = (int*)(ws + 114816);        // 33280
    float* slot_w = (float*)(ws + 148096);        // 33280
    unsigned short* act = (unsigned short*)(ws + 181504);     // 8320*1024*2 -> end 17220864
    // fallback-only dout region:
    unsigned short* dout = (unsigned short*)(ws + 17220864);  // 8320*2048*2 -> end 51299584
    const size_t needed_small = 51299584ull;
    // fast-path bf16 buffers (xb overlaps fallback's dout region — paths are exclusive)
    unsigned short* xb  = (unsigned short*)(ws + 17220864ull);   // 4096*2048*2  = 16 MB -> 33998080
    unsigned short* gwb = (unsigned short*)(ws + 33998080ull);   // 8*1024*2048*2 = 32 MB -> 67552512
    unsigned short* uwb = (unsigned short*)(ws + 67552512ull);   // 32 MB -> 101106944
    unsigned short* dwb = (unsigned short*)(ws + 101106944ull);  // 32 MB -> 134661376
    const size_t needed_big = 134661376ull;

    if (ws_size < needed_small) {
        noop_kernel<<<1, 64, 0, stream>>>();
        return;
    }

    init_kernel<<<1, 64, 0, stream>>>((int*)ws);

    if (ws_size >= needed_big) {
        router_kernel<<<T_TOKENS, 64, 0, stream>>>(x, cw, bias, counts, tok_e, tok_w, zero_w, xb);
        scan_kernel<<<1, 64, 0, stream>>>(counts, offs);
        place_kernel<<<(T_TOKENS + 255) / 256, 256, 0, stream>>>(tok_e, tok_w, offs, fill,
                                                                 token_list, slot_w, map);
        cvt3_kernel<<<4096, 256, 0, stream>>>(gw, uw, dw, gwb, uwb, dwb);
        preout_kernel<<<T_TOKENS, 256, 0, stream>>>(x, zero_w, out);
        gemm1_kernel<<<dim3(2 * IDIM / 128, 32, NEXP), 256, 0, stream>>>(xb, gwb, uwb, offs,
                                                                         token_list, slot_w, act);
        gemm2_kernel<<<dim3(HDIM / 128, 32, NEXP), 256, 0, stream>>>(act, dwb, offs,
                                                                     token_list, out);
    } else {
        router_kernel<<<T_TOKENS, 64, 0, stream>>>(x, cw, bias, counts, tok_e, tok_w, zero_w,
                                                   (unsigned short*)nullptr);
        scan_kernel<<<1, 64, 0, stream>>>(counts, offs);
        place_kernel<<<(T_TOKENS + 255) / 256, 256, 0, stream>>>(tok_e, tok_w, offs, fill,
                                                                 token_list, slot_w, map);
        gemm1_fb<<<dim3(IDIM / 128, 32, NEXP), 256, 0, stream>>>(x, gw, uw, offs,
                                                                 token_list, slot_w, act);
        gemm2_fb<<<dim3(HDIM / 128, 32, NEXP), 256, 0, stream>>>(act, dw, offs, dout);
        finalize_kernel<<<(T_TOKENS * HDIM / 8 + 255) / 256, 256, 0, stream>>>(x, dout, map,
                                                                               zero_w, out);
    }
}

// Round 6
// 491.663 us; speedup vs baseline: 1.0625x; 1.0560x over previous
//
#include <hip/hip_runtime.h>
#include <cstdint>

#define T_TOKENS 4096
#define HDIM 2048
#define IDIM 1024
#define NEXP 8
#define NTOT 12
#define MAX_SLOTS 8320   // 8192 + 128 pad for tile overshoot reads

typedef __bf16 bf16x8_t __attribute__((ext_vector_type(8)));
typedef float f32x4_t __attribute__((ext_vector_type(4)));
typedef unsigned short u16x8_t __attribute__((ext_vector_type(8)));
typedef unsigned short u16x4_t __attribute__((ext_vector_type(4)));

__device__ __forceinline__ unsigned short f2bf(float f) {
    unsigned int u = __builtin_bit_cast(unsigned int, f);
    u += 0x7fffu + ((u >> 16) & 1u);
    return (unsigned short)(u >> 16);
}
__device__ __forceinline__ float bfu2f(unsigned short u) {
    unsigned int v = ((unsigned int)u) << 16;
    return __builtin_bit_cast(float, v);
}
// async global->LDS, 16B per lane; LDS dest = wave-uniform base + lane*16
__device__ __forceinline__ void async16(const unsigned short* g, unsigned short* l) {
    __builtin_amdgcn_global_load_lds(
        (const unsigned int __attribute__((address_space(1)))*)g,
        (unsigned int __attribute__((address_space(3)))*)l,
        16, 0, 0);
}
__device__ __forceinline__ void async16f(const float* g, float* l) {
    __builtin_amdgcn_global_load_lds(
        (const unsigned int __attribute__((address_space(1)))*)g,
        (unsigned int __attribute__((address_space(3)))*)l,
        16, 0, 0);
}
// read 16 fp32, convert RNE to bf16, write 32B to LDS (fallback path only)
__device__ __forceinline__ void cvt16(const float* src, unsigned short* dst) {
    f32x4_t f0 = ((const f32x4_t*)src)[0];
    f32x4_t f1 = ((const f32x4_t*)src)[1];
    f32x4_t f2 = ((const f32x4_t*)src)[2];
    f32x4_t f3 = ((const f32x4_t*)src)[3];
    u16x8_t a, b;
#pragma unroll
    for (int j = 0; j < 4; ++j) { a[j] = f2bf(f0[j]); a[4 + j] = f2bf(f1[j]); }
#pragma unroll
    for (int j = 0; j < 4; ++j) { b[j] = f2bf(f2[j]); b[4 + j] = f2bf(f3[j]); }
    ((u16x8_t*)dst)[0] = a;
    ((u16x8_t*)dst)[1] = b;
}

// ---------------- zero-init metadata ----------------
__global__ void init_kernel(int* __restrict__ meta) {
    int i = threadIdx.x;
    if (i < 32) meta[i] = 0;
}

__global__ void noop_kernel() {}

// ---------------- Router (fp32): logits->softmax->top2; also emits bf16 x ----------------
__global__ void router_kernel(const float* __restrict__ x,
                              const float* __restrict__ cw,
                              const float* __restrict__ bias,
                              int* __restrict__ counts,
                              int* __restrict__ tok_e,
                              float* __restrict__ tok_w,
                              float* __restrict__ zero_w,
                              unsigned short* __restrict__ xb) {
    const int token = blockIdx.x;
    const int ln = threadIdx.x;  // 0..63
    const float* xr = x + (size_t)token * HDIM;
    float acc[NTOT];
#pragma unroll
    for (int e = 0; e < NTOT; ++e) acc[e] = 0.f;
    for (int h0 = ln * 4; h0 < HDIM; h0 += 256) {
        f32x4_t xv = *(const f32x4_t*)(xr + h0);
        if (xb) {
            u16x4_t o;
#pragma unroll
            for (int j = 0; j < 4; ++j) o[j] = f2bf(xv[j]);
            *(u16x4_t*)(xb + (size_t)token * HDIM + h0) = o;
        }
#pragma unroll
        for (int e = 0; e < NTOT; ++e) {
            f32x4_t wv = *(const f32x4_t*)(cw + e * HDIM + h0);
            acc[e] += xv[0] * wv[0] + xv[1] * wv[1] + xv[2] * wv[2] + xv[3] * wv[3];
        }
    }
#pragma unroll
    for (int e = 0; e < NTOT; ++e) {
        float v = acc[e];
#pragma unroll
        for (int s = 32; s > 0; s >>= 1) v += __shfl_xor(v, s, 64);
        acc[e] = v;
    }
    if (ln == 0) {
        float mx = acc[0];
#pragma unroll
        for (int e = 1; e < NTOT; ++e) mx = fmaxf(mx, acc[e]);
        float p[NTOT];
        float sum = 0.f;
#pragma unroll
        for (int e = 0; e < NTOT; ++e) { p[e] = __expf(acc[e] - mx); sum += p[e]; }
        float inv = 1.f / sum;
#pragma unroll
        for (int e = 0; e < NTOT; ++e) p[e] *= inv;
        float b[NTOT];
#pragma unroll
        for (int e = 0; e < NTOT; ++e) b[e] = p[e] + bias[e];
        int i0 = 0; float v0 = b[0];
#pragma unroll
        for (int e = 1; e < NTOT; ++e) if (b[e] > v0) { v0 = b[e]; i0 = e; }
        int i1 = -1; float v1 = -3.0e38f;
#pragma unroll
        for (int e = 0; e < NTOT; ++e) if (e != i0 && b[e] > v1) { v1 = b[e]; i1 = e; }
        if (i1 < 0) i1 = (i0 == 0) ? 1 : 0;  // defensive
        float w0 = p[i0] * 1.5f, w1 = p[i1] * 1.5f;
        tok_e[2 * token] = i0; tok_e[2 * token + 1] = i1;
        tok_w[2 * token] = w0; tok_w[2 * token + 1] = w1;
        float zw = 0.f;
        if (i0 >= NEXP) zw += w0; else atomicAdd(&counts[i0], 1);
        if (i1 >= NEXP) zw += w1; else atomicAdd(&counts[i1], 1);
        zero_w[token] = zw;
    }
}

// ---------------- prefix scan over 8 experts ----------------
__global__ void scan_kernel(const int* __restrict__ counts, int* __restrict__ offs) {
    if (threadIdx.x == 0 && blockIdx.x == 0) {
        int a = 0;
        for (int e = 0; e < NEXP; ++e) {
            offs[e] = a;
            int c = counts[e];
            if (c < 0) c = 0;
            if (c > T_TOKENS) c = T_TOKENS;
            a += c;
        }
        if (a > 2 * T_TOKENS) a = 2 * T_TOKENS;
        offs[NEXP] = a;
    }
}

// ---------------- place tokens into per-expert contiguous lists ----------------
__global__ void place_kernel(const int* __restrict__ tok_e, const float* __restrict__ tok_w,
                             const int* __restrict__ offs, int* __restrict__ fill,
                             int* __restrict__ token_list, float* __restrict__ slot_w,
                             int* __restrict__ map) {
    int token = blockIdx.x * blockDim.x + threadIdx.x;
    if (token >= T_TOKENS) return;
#pragma unroll
    for (int j = 0; j < 2; ++j) {
        int e = tok_e[2 * token + j];
        int m = -1;
        if (e >= 0 && e < NEXP) {
            int pos = atomicAdd(&fill[e], 1);
            int slot = offs[e] + pos;
            if (slot >= 0 && slot < 2 * T_TOKENS) {
                token_list[slot] = token;
                slot_w[slot] = tok_w[2 * token + j];
                m = slot;
            }
        }
        map[2 * token + j] = m;
    }
}

// ============ GEMM1: A bf16 (xb, async), B fp32 DIRECT (gate/up, async,
// stage-time interleave into packed layout), in-register fp32->bf16 after ds_read.
// B LDS is XOR-swizzled per rule 21: source 16B-block = (ln&7)^(ln>>3), read-side
// block = logical ^ (row&7) -> exact 2-way bank access on ds_read_b128.
// Packed row p (j=p>>5, r=p&31): r<16 -> gate[16j+r], else up[16j+r-16].
__launch_bounds__(256, 3)
__global__ void gemm1_kernel(const unsigned short* __restrict__ xb,
                             const float* __restrict__ gate_w,
                             const float* __restrict__ up_w,
                             const int* __restrict__ offs,
                             const int* __restrict__ token_list,
                             const float* __restrict__ slot_w,
                             unsigned short* __restrict__ act) {
    const int e = blockIdx.z;
    const int off = offs[e];
    int Me = offs[e + 1] - off;
    if (Me < 0) Me = 0;
    if (Me > T_TOKENS) Me = T_TOKENS;
    const int m0 = blockIdx.y * 128;
    if (m0 >= Me) return;
    const int n0 = blockIdx.x * 128;  // packed-N (2048 wide)

    __shared__ __align__(16) unsigned short As[128][32];
    __shared__ __align__(16) float Bsf[128][32];

    const int tid = threadIdx.x;
    const int wv = tid >> 6, ln = tid & 63;
    const int sc = (ln & 3) * 8;
    const int R = ln >> 2;

    // A staging: wave wv stages rows [wv*16, +16) and +64 (gathered tokens), bf16
    int tr0 = m0 + wv * 16 + R;      if (tr0 >= Me) tr0 = Me - 1;
    int tr1 = m0 + 64 + wv * 16 + R; if (tr1 >= Me) tr1 = Me - 1;
    int tok0 = token_list[off + tr0]; if (tok0 < 0 || tok0 >= T_TOKENS) tok0 = 0;
    int tok1 = token_list[off + tr1]; if (tok1 < 0 || tok1 >= T_TOKENS) tok1 = 0;
    const unsigned short* aA0 = xb + (size_t)tok0 * HDIM + sc;
    const unsigned short* aA1 = xb + (size_t)tok1 * HDIM + sc;
    unsigned short* lA0 = &As[wv * 16][0];
    unsigned short* lA1 = &As[64 + wv * 16][0];

    // B staging fp32: 4 issues q=0..3; per issue, wave wv covers packed rows
    // q*32 + wv*8 + (ln>>3); lane col-block (ln&7) (swizzled source col-block).
    // Packed row -> j=q, r=wv*8+(ln>>3): wv<2 -> gate row 16q+(wv&1)*8+(ln>>3),
    // wv>=2 -> up row 16q+(wv&1)*8+(ln>>3).
    const float* wsel = (wv < 2) ? gate_w : up_w;
    const float* aB = wsel + ((size_t)e * IDIM + (n0 >> 1) + (wv & 1) * 8 + (ln >> 3)) * HDIM
                      + (((ln & 7) ^ (ln >> 3)) * 4);
    float* lB0 = &Bsf[wv * 8][0];
    float* lB1 = &Bsf[32 + wv * 8][0];
    float* lB2 = &Bsf[64 + wv * 8][0];
    float* lB3 = &Bsf[96 + wv * 8][0];

    const int wm = wv & 1, wn = wv >> 1;
    const int fr = ln & 15;
    const int fk = (ln >> 4) * 8;
    const int cb0 = fk >> 2;  // logical 16B-block of the fragment's K-slice

    f32x4_t acc[4][4] = {};

    for (int k0 = 0; k0 < HDIM; k0 += 32) {
        async16(aA0 + k0, lA0);
        async16(aA1 + k0, lA1);
        async16f(aB + k0, lB0);
        async16f(aB + (size_t)16 * HDIM + k0, lB1);
        async16f(aB + (size_t)32 * HDIM + k0, lB2);
        async16f(aB + (size_t)48 * HDIM + k0, lB3);
        __syncthreads();
        bf16x8_t af[4], bfr[4];
#pragma unroll
        for (int t = 0; t < 4; ++t) {
            af[t] = *(const bf16x8_t*)&As[wm * 64 + t * 16 + fr][fk];
            const int row = wn * 64 + t * 16 + fr;
            const int rx = row & 7;
            f32x4_t lo = *(const f32x4_t*)&Bsf[row][(cb0 ^ rx) * 4];
            f32x4_t hi = *(const f32x4_t*)&Bsf[row][((cb0 + 1) ^ rx) * 4];
#pragma unroll
            for (int j = 0; j < 4; ++j) {
                bfr[t][j] = (__bf16)lo[j];
                bfr[t][4 + j] = (__bf16)hi[j];
            }
        }
#pragma unroll
        for (int mt = 0; mt < 4; ++mt)
#pragma unroll
            for (int nt = 0; nt < 4; ++nt)
                acc[mt][nt] = __builtin_amdgcn_mfma_f32_16x16x32_bf16(af[mt], bfr[nt], acc[mt][nt], 0, 0, 0);
        __syncthreads();
    }

    // Epilogue: packed col p = n0 + wn*64 + nt*16 + fr.
    // nt even -> gate of intermediate i; nt odd -> up of the SAME i,
    // i = n0/2 + wn*32 + (nt>>1)*16 + fr  (lane-local pairing).
    const int ibase = (n0 >> 1) + wn * 32;
#pragma unroll
    for (int mt = 0; mt < 4; ++mt) {
#pragma unroll
        for (int r = 0; r < 4; ++r) {
            int rloc = wm * 64 + mt * 16 + (ln >> 4) * 4 + r;
            int grow = m0 + rloc;
            if (grow < Me) {
                float w = slot_w[off + grow];
                size_t rb = (size_t)(off + grow) * IDIM + ibase;
#pragma unroll
                for (int t = 0; t < 2; ++t) {
                    float g = acc[mt][2 * t][r];
                    float u = acc[mt][2 * t + 1][r];
                    float s = g / (1.f + __expf(-g));
                    act[rb + t * 16 + fr] = f2bf(s * u * w);
                }
            }
        }
    }
}

// ============ GEMM2: A bf16 (act, async), B fp32 DIRECT (down_w, async, swizzled),
// in-register cvt; epilogue stores bf16 rows to dout (finalize combines). ============
__launch_bounds__(256, 3)
__global__ void gemm2_kernel(const unsigned short* __restrict__ act,
                             const float* __restrict__ dwn,
                             const int* __restrict__ offs,
                             unsigned short* __restrict__ dout) {
    const int e = blockIdx.z;
    const int off = offs[e];
    int Me = offs[e + 1] - off;
    if (Me < 0) Me = 0;
    if (Me > T_TOKENS) Me = T_TOKENS;
    const int m0 = blockIdx.y * 128;
    if (m0 >= Me) return;
    const int n0 = blockIdx.x * 128;

    __shared__ __align__(16) unsigned short As[128][32];
    __shared__ __align__(16) float Bsf[128][32];

    const int tid = threadIdx.x;
    const int wv = tid >> 6, ln = tid & 63;
    const int sc = (ln & 3) * 8;
    const int R = ln >> 2;

    // A staging: wave wv stages rows [wv*16, +16) and +64 (bf16 act)
    int ar0 = off + m0 + wv * 16 + R;      if (ar0 >= MAX_SLOTS) ar0 = MAX_SLOTS - 1;
    int ar1 = off + m0 + 64 + wv * 16 + R; if (ar1 >= MAX_SLOTS) ar1 = MAX_SLOTS - 1;
    const unsigned short* aA0 = act + (size_t)ar0 * IDIM + sc;
    const unsigned short* aA1 = act + (size_t)ar1 * IDIM + sc;
    unsigned short* lA0 = &As[wv * 16][0];
    unsigned short* lA1 = &As[64 + wv * 16][0];

    // B staging fp32: rows n0 + q*32 + wv*8 + (ln>>3) of down_w[e], swizzled col-block
    const float* aB = dwn + (size_t)e * HDIM * IDIM +
                      (size_t)(n0 + wv * 8 + (ln >> 3)) * IDIM + (((ln & 7) ^ (ln >> 3)) * 4);
    float* lB0 = &Bsf[wv * 8][0];
    float* lB1 = &Bsf[32 + wv * 8][0];
    float* lB2 = &Bsf[64 + wv * 8][0];
    float* lB3 = &Bsf[96 + wv * 8][0];

    const int wm = wv & 1, wn = wv >> 1;
    const int fr = ln & 15;
    const int fk = (ln >> 4) * 8;
    const int cb0 = fk >> 2;

    f32x4_t acc[4][4] = {};

    for (int k0 = 0; k0 < IDIM; k0 += 32) {
        async16(aA0 + k0, lA0);
        async16(aA1 + k0, lA1);
        async16f(aB + k0, lB0);
        async16f(aB + (size_t)32 * IDIM + k0, lB1);
        async16f(aB + (size_t)64 * IDIM + k0, lB2);
        async16f(aB + (size_t)96 * IDIM + k0, lB3);
        __syncthreads();
        bf16x8_t af[4], bfr[4];
#pragma unroll
        for (int t = 0; t < 4; ++t) {
            af[t] = *(const bf16x8_t*)&As[wm * 64 + t * 16 + fr][fk];
            const int row = wn * 64 + t * 16 + fr;
            const int rx = row & 7;
            f32x4_t lo = *(const f32x4_t*)&Bsf[row][(cb0 ^ rx) * 4];
            f32x4_t hi = *(const f32x4_t*)&Bsf[row][((cb0 + 1) ^ rx) * 4];
#pragma unroll
            for (int j = 0; j < 4; ++j) {
                bfr[t][j] = (__bf16)lo[j];
                bfr[t][4 + j] = (__bf16)hi[j];
            }
        }
#pragma unroll
        for (int mt = 0; mt < 4; ++mt)
#pragma unroll
            for (int nt = 0; nt < 4; ++nt)
                acc[mt][nt] = __builtin_amdgcn_mfma_f32_16x16x32_bf16(af[mt], bfr[nt], acc[mt][nt], 0, 0, 0);
        __syncthreads();
    }

#pragma unroll
    for (int mt = 0; mt < 4; ++mt) {
#pragma unroll
        for (int r = 0; r < 4; ++r) {
            int rloc = wm * 64 + mt * 16 + (ln >> 4) * 4 + r;
            int grow = m0 + rloc;
            if (grow < Me) {
                size_t rb = (size_t)(off + grow) * HDIM + n0;
#pragma unroll
                for (int nt = 0; nt < 4; ++nt)
                    dout[rb + wn * 64 + nt * 16 + fr] = f2bf(acc[mt][nt][r]);
            }
        }
    }
}

// ---------------- FALLBACK GEMMs (fp32 weights, cvt16 staging) ----------------
__launch_bounds__(256, 2)
__global__ void gemm1_fb(const float* __restrict__ x,
                         const float* __restrict__ gate_w,
                         const float* __restrict__ up_w,
                         const int* __restrict__ offs,
                         const int* __restrict__ token_list,
                         const float* __restrict__ slot_w,
                         unsigned short* __restrict__ act) {
    const int e = blockIdx.z;
    const int off = offs[e];
    int Me = offs[e + 1] - off;
    if (Me < 0) Me = 0;
    if (Me > T_TOKENS) Me = T_TOKENS;
    const int m0 = blockIdx.y * 128;
    if (m0 >= Me) return;
    const int n0 = blockIdx.x * 128;

    __shared__ __align__(16) unsigned short As[128][32];
    __shared__ __align__(16) unsigned short Gs[128][32];
    __shared__ __align__(16) unsigned short Us[128][32];

    const int tid = threadIdx.x;
    const int srow = tid >> 1;
    const int shalf = (tid & 1) * 16;

    int tr = m0 + srow; if (tr >= Me) tr = Me - 1;
    int tok = token_list[off + tr];
    if (tok < 0 || tok >= T_TOKENS) tok = 0;
    const float* aA = x + (size_t)tok * HDIM + shalf;
    const float* aG = gate_w + (size_t)e * IDIM * HDIM + (size_t)(n0 + srow) * HDIM + shalf;
    const float* aU = up_w + (size_t)e * IDIM * HDIM + (size_t)(n0 + srow) * HDIM + shalf;
    unsigned short* lA = &As[srow][shalf];
    unsigned short* lG = &Gs[srow][shalf];
    unsigned short* lU = &Us[srow][shalf];

    const int wv = tid >> 6, ln = tid & 63;
    const int wm = wv & 1, wn = wv >> 1;
    const int fr = ln & 15;
    const int fk = (ln >> 4) * 8;

    f32x4_t accg[4][4] = {};
    f32x4_t accu[4][4] = {};

    for (int k0 = 0; k0 < HDIM; k0 += 32) {
        cvt16(aA + k0, lA);
        cvt16(aG + k0, lG);
        cvt16(aU + k0, lU);
        __syncthreads();
        bf16x8_t af[4], gf[4], uf[4];
#pragma unroll
        for (int t = 0; t < 4; ++t) {
            af[t] = *(const bf16x8_t*)&As[wm * 64 + t * 16 + fr][fk];
            gf[t] = *(const bf16x8_t*)&Gs[wn * 64 + t * 16 + fr][fk];
            uf[t] = *(const bf16x8_t*)&Us[wn * 64 + t * 16 + fr][fk];
        }
#pragma unroll
        for (int mt = 0; mt < 4; ++mt)
#pragma unroll
            for (int nt = 0; nt < 4; ++nt) {
                accg[mt][nt] = __builtin_amdgcn_mfma_f32_16x16x32_bf16(af[mt], gf[nt], accg[mt][nt], 0, 0, 0);
                accu[mt][nt] = __builtin_amdgcn_mfma_f32_16x16x32_bf16(af[mt], uf[nt], accu[mt][nt], 0, 0, 0);
            }
        __syncthreads();
    }

#pragma unroll
    for (int mt = 0; mt < 4; ++mt) {
#pragma unroll
        for (int r = 0; r < 4; ++r) {
            int rloc = wm * 64 + mt * 16 + (ln >> 4) * 4 + r;
            int grow = m0 + rloc;
            if (grow < Me) {
                float w = slot_w[off + grow];
                size_t rb = (size_t)(off + grow) * IDIM + n0;
#pragma unroll
                for (int nt = 0; nt < 4; ++nt) {
                    float g = accg[mt][nt][r];
                    float u = accu[mt][nt][r];
                    float s = g / (1.f + __expf(-g));
                    act[rb + wn * 64 + nt * 16 + fr] = f2bf(s * u * w);
                }
            }
        }
    }
}

__launch_bounds__(256, 2)
__global__ void gemm2_fb(const unsigned short* __restrict__ act,
                         const float* __restrict__ dwn,
                         const int* __restrict__ offs,
                         unsigned short* __restrict__ dout) {
    const int e = blockIdx.z;
    const int off = offs[e];
    int Me = offs[e + 1] - off;
    if (Me < 0) Me = 0;
    if (Me > T_TOKENS) Me = T_TOKENS;
    const int m0 = blockIdx.y * 128;
    if (m0 >= Me) return;
    const int n0 = blockIdx.x * 128;

    __shared__ __align__(16) unsigned short As[128][32];
    __shared__ __align__(16) unsigned short Bs[128][32];

    const int tid = threadIdx.x;
    const int wv = tid >> 6, ln = tid & 63;

    const int sr0 = wv * 16 + (ln >> 2);
    const int sc = (ln & 3) * 8;
    int ar0 = off + m0 + sr0;      if (ar0 >= MAX_SLOTS) ar0 = MAX_SLOTS - 1;
    int ar1 = off + m0 + 64 + sr0; if (ar1 >= MAX_SLOTS) ar1 = MAX_SLOTS - 1;
    const unsigned short* aA0 = act + (size_t)ar0 * IDIM + sc;
    const unsigned short* aA1 = act + (size_t)ar1 * IDIM + sc;
    unsigned short* lA0 = &As[wv * 16][0];
    unsigned short* lA1 = &As[64 + wv * 16][0];

    const int srow = tid >> 1;
    const int shalf = (tid & 1) * 16;
    const float* aB = dwn + (size_t)e * HDIM * IDIM + (size_t)(n0 + srow) * IDIM + shalf;
    unsigned short* lB = &Bs[srow][shalf];

    const int wm = wv & 1, wn = wv >> 1;
    const int fr = ln & 15;
    const int fk = (ln >> 4) * 8;

    f32x4_t acc[4][4] = {};

    for (int k0 = 0; k0 < IDIM; k0 += 32) {
        async16(aA0 + k0, lA0);
        async16(aA1 + k0, lA1);
        cvt16(aB + k0, lB);
        __syncthreads();
        bf16x8_t af[4], bfr[4];
#pragma unroll
        for (int t = 0; t < 4; ++t) {
            af[t] = *(const bf16x8_t*)&As[wm * 64 + t * 16 + fr][fk];
            bfr[t] = *(const bf16x8_t*)&Bs[wn * 64 + t * 16 + fr][fk];
        }
#pragma unroll
        for (int mt = 0; mt < 4; ++mt)
#pragma unroll
            for (int nt = 0; nt < 4; ++nt)
                acc[mt][nt] = __builtin_amdgcn_mfma_f32_16x16x32_bf16(af[mt], bfr[nt], acc[mt][nt], 0, 0, 0);
        __syncthreads();
    }

#pragma unroll
    for (int mt = 0; mt < 4; ++mt) {
#pragma unroll
        for (int r = 0; r < 4; ++r) {
            int rloc = wm * 64 + mt * 16 + (ln >> 4) * 4 + r;
            int grow = m0 + rloc;
            if (grow < Me) {
                size_t rb = (size_t)(off + grow) * HDIM + n0;
#pragma unroll
                for (int nt = 0; nt < 4; ++nt)
                    dout[rb + wn * 64 + nt * 16 + fr] = f2bf(acc[mt][nt][r]);
            }
        }
    }
}

// ---------------- finalize: out(fp32) = sum(slot rows bf16) + zero_w * x(fp32) ----------------
__global__ void finalize_kernel(const float* __restrict__ x,
                                const unsigned short* __restrict__ dout,
                                const int* __restrict__ map,
                                const float* __restrict__ zero_w,
                                float* __restrict__ out) {
    int gid = blockIdx.x * blockDim.x + threadIdx.x;  // T*H/8 total
    int token = gid >> 8;
    int hg = (gid & 255) * 8;
    int s0 = map[2 * token], s1 = map[2 * token + 1];
    float zw = zero_w[token];
    size_t base = (size_t)token * HDIM + hg;
    f32x4_t x0 = *(const f32x4_t*)(x + base);
    f32x4_t x1 = *(const f32x4_t*)(x + base + 4);
    float o[8];
#pragma unroll
    for (int j = 0; j < 4; ++j) { o[j] = zw * x0[j]; o[4 + j] = zw * x1[j]; }
    if (s0 >= 0 && s0 < 2 * T_TOKENS) {
        u16x8_t d = *(const u16x8_t*)(dout + (size_t)s0 * HDIM + hg);
#pragma unroll
        for (int j = 0; j < 8; ++j) o[j] += bfu2f(d[j]);
    }
    if (s1 >= 0 && s1 < 2 * T_TOKENS) {
        u16x8_t d = *(const u16x8_t*)(dout + (size_t)s1 * HDIM + hg);
#pragma unroll
        for (int j = 0; j < 8; ++j) o[j] += bfu2f(d[j]);
    }
    f32x4_t o0, o1;
#pragma unroll
    for (int j = 0; j < 4; ++j) { o0[j] = o[j]; o1[j] = o[4 + j]; }
    *(f32x4_t*)(out + base) = o0;
    *(f32x4_t*)(out + base + 4) = o1;
}

// ---------------- launch ----------------
extern "C" void kernel_launch(void* const* d_in, const int* in_sizes, int n_in,
                              void* d_out, int out_size, void* d_ws, size_t ws_size,
                              hipStream_t stream) {
    const float* x = (const float*)d_in[0];
    const float* cw = (const float*)d_in[1];
    const float* bias = (const float*)d_in[2];
    const float* gw = (const float*)d_in[3];
    const float* uw = (const float*)d_in[4];
    const float* dw = (const float*)d_in[5];
    float* out = (float*)d_out;

    char* ws = (char*)d_ws;
    int* counts = (int*)(ws + 0);                 // 32 B
    int* fill = (int*)(ws + 32);                  // 32 B
    int* offs = (int*)(ws + 64);                  // 64 B (9 ints)
    int* tok_e = (int*)(ws + 128);                // 32768
    float* tok_w = (float*)(ws + 32896);          // 32768
    float* zero_w = (float*)(ws + 65664);         // 16384
    int* map = (int*)(ws + 82048);                // 32768
    int* token_list = (int*)(ws + 114816);        // 33280
    float* slot_w = (float*)(ws + 148096);        // 33280
    unsigned short* act = (unsigned short*)(ws + 181504);     // 8320*1024*2 -> end 17220864
    unsigned short* dout = (unsigned short*)(ws + 17220864);  // 8320*2048*2 -> end 51299584
    const size_t needed_small = 51299584ull;
    // fast path additionally needs bf16 x
    unsigned short* xb = (unsigned short*)(ws + 51299584ull);  // 4096*2048*2 = 16 MB -> 68076800
    const size_t needed_big = 68076800ull;

    if (ws_size < needed_small) {
        noop_kernel<<<1, 64, 0, stream>>>();
        return;
    }

    init_kernel<<<1, 64, 0, stream>>>((int*)ws);

    if (ws_size >= needed_big) {
        router_kernel<<<T_TOKENS, 64, 0, stream>>>(x, cw, bias, counts, tok_e, tok_w, zero_w, xb);
        scan_kernel<<<1, 64, 0, stream>>>(counts, offs);
        place_kernel<<<(T_TOKENS + 255) / 256, 256, 0, stream>>>(tok_e, tok_w, offs, fill,
                                                                 token_list, slot_w, map);
        gemm1_kernel<<<dim3(2 * IDIM / 128, 32, NEXP), 256, 0, stream>>>(xb, gw, uw, offs,
                                                                         token_list, slot_w, act);
        gemm2_kernel<<<dim3(HDIM / 128, 32, NEXP), 256, 0, stream>>>(act, dw, offs, dout);
    } else {
        router_kernel<<<T_TOKENS, 64, 0, stream>>>(x, cw, bias, counts, tok_e, tok_w, zero_w,
                                                   (unsigned short*)nullptr);
        scan_kernel<<<1, 64, 0, stream>>>(counts, offs);
        place_kernel<<<(T_TOKENS + 255) / 256, 256, 0, stream>>>(tok_e, tok_w, offs, fill,
                                                                 token_list, slot_w, map);
        gemm1_fb<<<dim3(IDIM / 128, 32, NEXP), 256, 0, stream>>>(x, gw, uw, offs,
                                                                 token_list, slot_w, act);
        gemm2_fb<<<dim3(HDIM / 128, 32, NEXP), 256, 0, stream>>>(act, dw, offs, dout);
    }

    finalize_kernel<<<(T_TOKENS * HDIM / 8 + 255) / 256, 256, 0, stream>>>(x, dout, map,
                                                                           zero_w, out);
}